// Round 11
// baseline (805.866 us; speedup 1.0000x reference)
//
#include <hip/hip_runtime.h>
#include <hip/hip_bf16.h>

using bf16 = __hip_bfloat16;

#define D_DIM   192
#define N_DIM   3072
#define NHEAD   4
#define T_SEQ   1024
#define HN      12288      // NHEAD * N_DIM
#define NP2     1536       // N_DIM/2
#define VOCABSZ 256
#define NLAYER  4
#define LN_EPS  1e-5f
#define TWO_PI  6.2831853071795864f

typedef __attribute__((ext_vector_type(8))) short          s16x8;
typedef __attribute__((ext_vector_type(8))) unsigned short u16x8;
typedef __attribute__((ext_vector_type(4))) float          f32x4;

__device__ __forceinline__ float b2f(bf16 v) { return __bfloat162float(v); }
__device__ __forceinline__ float us2f(unsigned short u) {
    unsigned int x = ((unsigned int)u) << 16;
    return __builtin_bit_cast(float, x);
}
__device__ __forceinline__ unsigned short f2us(float f) {
    bf16 b = __float2bfloat16(f);
    return __builtin_bit_cast(unsigned short, b);
}

// sentinel: encode ws_size into output (fires only if ws too small)
__global__ void fill_out(float* __restrict__ out, float val, int nelem) {
    int i = blockIdx.x * 256 + threadIdx.x;
    if (i < nelem) out[i] = val;
}

// ---------------------------------------------------------------------------
// Tiled transpose + fp32->bf16: in fp32 [R][C] -> out bf16 [C][R].
// ---------------------------------------------------------------------------
__global__ void t_cvt(const float* __restrict__ in, bf16* __restrict__ out,
                      int R, int C, long inZ, long outZ) {
    __shared__ float tile[64][65];
    in  += inZ  * blockIdx.z;
    out += outZ * blockIdx.z;
    const int tx = threadIdx.x & 63, ty = threadIdx.x >> 6;
    const int r0 = blockIdx.y * 64, c0 = blockIdx.x * 64;
    #pragma unroll
    for (int rr = 0; rr < 16; rr++) {
        int row = ty * 16 + rr;
        tile[row][tx] = in[(size_t)(r0 + row) * C + c0 + tx];
    }
    __syncthreads();
    #pragma unroll
    for (int rr = 0; rr < 16; rr++) {
        int row = ty * 16 + rr;
        out[(size_t)(c0 + row) * R + r0 + tx] = __float2bfloat16(tile[tx][row]);
    }
}

// ---------------------------------------------------------------------------
// Wave-per-row LN family (64 threads/block, 3 elems/lane, butterfly reduce)
// ---------------------------------------------------------------------------
__device__ __forceinline__ void wave_sum2(float& s, float& ss) {
    #pragma unroll
    for (int off = 1; off < 64; off <<= 1) {
        s  += __shfl_xor(s,  off, 64);
        ss += __shfl_xor(ss, off, 64);
    }
}

__global__ void k_embed(const int* __restrict__ idx, const float* __restrict__ emb,
                        const float* __restrict__ pos, float* __restrict__ x) {
    int t = blockIdx.x, l = threadIdx.x;
    int tok = idx[t];
    const float* e = emb + tok * D_DIM;
    const float* p = pos + t * D_DIM;
    float v0 = e[l] + p[l], v1 = e[l + 64] + p[l + 64], v2 = e[l + 128] + p[l + 128];
    float s = v0 + v1 + v2, ss = v0 * v0 + v1 * v1 + v2 * v2;
    wave_sum2(s, ss);
    float m = s / D_DIM, r = rsqrtf(ss / D_DIM - m * m + LN_EPS);
    float* xr = x + t * D_DIM;
    xr[l] = (v0 - m) * r; xr[l + 64] = (v1 - m) * r; xr[l + 128] = (v2 - m) * r;
}

__global__ void k_ln(float* __restrict__ buf) {
    int l = threadIdx.x;
    float* row = buf + (size_t)blockIdx.x * D_DIM;
    float v0 = row[l], v1 = row[l + 64], v2 = row[l + 128];
    float s = v0 + v1 + v2, ss = v0 * v0 + v1 * v1 + v2 * v2;
    wave_sum2(s, ss);
    float m = s / D_DIM, r = rsqrtf(ss / D_DIM - m * m + LN_EPS);
    row[l] = (v0 - m) * r; row[l + 64] = (v1 - m) * r; row[l + 128] = (v2 - m) * r;
}

// x = LN(x + LN(sum of 8 split-K partial slabs))
__global__ void k_resid8(float* __restrict__ x, const float* __restrict__ P) {
    int l = threadIdx.x, t = blockIdx.x;
    float y0 = 0.f, y1 = 0.f, y2 = 0.f;
    #pragma unroll
    for (int p = 0; p < 8; p++) {
        const float* r = P + (size_t)p * T_SEQ * D_DIM + (size_t)t * D_DIM;
        y0 += r[l]; y1 += r[l + 64]; y2 += r[l + 128];
    }
    float* xr = x + (size_t)t * D_DIM;
    float s = y0 + y1 + y2, ss = y0 * y0 + y1 * y1 + y2 * y2;
    wave_sum2(s, ss);
    float m1 = s / D_DIM, r1 = rsqrtf(ss / D_DIM - m1 * m1 + LN_EPS);
    float v0 = xr[l] + (y0 - m1) * r1;
    float v1 = xr[l + 64] + (y1 - m1) * r1;
    float v2 = xr[l + 128] + (y2 - m1) * r1;
    s = v0 + v1 + v2; ss = v0 * v0 + v1 * v1 + v2 * v2;
    wave_sum2(s, ss);
    float m2 = s / D_DIM, r2 = rsqrtf(ss / D_DIM - m2 * m2 + LN_EPS);
    xr[l] = (v0 - m2) * r2; xr[l + 64] = (v1 - m2) * r2; xr[l + 128] = (v2 - m2) * r2;
}

// RoPE cos/sin tables, interleaved bf16 pairs csT[t][p] = (cos, sin)
__global__ void k_tables(ushort2* __restrict__ csT) {
    int gid = blockIdx.x * 256 + threadIdx.x;
    int t = gid / NP2, p = gid % NP2;
    float qf = (float)(2 * p);
    float f = 1.0f / powf(65536.0f, qf / 3072.0f) / (float)TWO_PI;
    float ph = fmodf((float)t * f, 1.0f) * (float)TWO_PI;
    ushort2 cs;
    cs.x = f2us(cosf(ph));
    cs.y = f2us(sinf(ph));
    csT[gid] = cs;
}

// ---------------------------------------------------------------------------
// scores128: sc[h,t,s] = dot(qr[t,h], qr[s,h]) for s<t, else 0.
// 128x128 block tile, 4 waves x (64x64), BK=32, triangular grid (36/head).
// ---------------------------------------------------------------------------
__launch_bounds__(256)
__global__ void scores128(const bf16* __restrict__ qr, bf16* __restrict__ sc) {
    const int h = blockIdx.z;
    int L = blockIdx.x;
    int i = 0;
    while (((i + 1) * (i + 2)) >> 1 <= L) ++i;
    int j = L - ((i * (i + 1)) >> 1);
    const int t0 = i * 128, s0 = j * 128;

    __shared__ short As[128][40];
    __shared__ short Bs[128][40];

    const int tid = threadIdx.x;
    const int lane = tid & 63, w = tid >> 6, qd = lane >> 4, lc = lane & 15;
    const int wtm = (w >> 1) * 64, wtn = (w & 1) * 64;

    const bf16* gA = qr + (size_t)t0 * HN + h * N_DIM;
    const bf16* gB = qr + (size_t)s0 * HN + h * N_DIM;

    f32x4 acc[4][4] = {};

    for (int k0 = 0; k0 < N_DIM; k0 += 32) {
        #pragma unroll
        for (int c = 0; c < 2; c++) {
            int ch = tid + c * 256;
            int row = ch >> 2, kq = (ch & 3) * 8;
            *(u16x8*)&As[row][kq] = *(const u16x8*)(gA + (size_t)row * HN + k0 + kq);
            *(u16x8*)&Bs[row][kq] = *(const u16x8*)(gB + (size_t)row * HN + k0 + kq);
        }
        __syncthreads();
        s16x8 a[4], b[4];
        #pragma unroll
        for (int m = 0; m < 4; m++) a[m] = *(const s16x8*)&As[wtm + m * 16 + lc][qd * 8];
        #pragma unroll
        for (int n = 0; n < 4; n++) b[n] = *(const s16x8*)&Bs[wtn + n * 16 + lc][qd * 8];
        #pragma unroll
        for (int m = 0; m < 4; m++)
            #pragma unroll
            for (int n = 0; n < 4; n++)
                acc[m][n] = __builtin_amdgcn_mfma_f32_16x16x32_bf16(a[m], b[n], acc[m][n], 0, 0, 0);
        __syncthreads();
    }

    bf16* C = sc + (size_t)h * T_SEQ * T_SEQ;
    const bool diag = (i == j);
    #pragma unroll
    for (int m = 0; m < 4; m++) {
        #pragma unroll
        for (int r = 0; r < 4; r++) {
            int t = t0 + wtm + m * 16 + qd * 4 + r;
            #pragma unroll
            for (int n = 0; n < 4; n++) {
                int s = s0 + wtn + n * 16 + lc;
                float v = (diag && s >= t) ? 0.f : acc[m][n][r];
                C[(size_t)t * T_SEQ + s] = __float2bfloat16(v);
            }
        }
    }
}

// ---------------------------------------------------------------------------
// scores fallback (no qr buffer): 64x64, rope fused into staging.
// ---------------------------------------------------------------------------
__device__ __forceinline__ void stage_rope8(short* dst, const bf16* src,
                                            const ushort2* csP) {
    u16x8 v  = *(const u16x8*)src;
    u16x8 cs = *(const u16x8*)csP;
    u16x8 o;
    #pragma unroll
    for (int i = 0; i < 4; i++) {
        float e  = us2f(v[2 * i]), od = us2f(v[2 * i + 1]);
        float c  = us2f(cs[2 * i]), s = us2f(cs[2 * i + 1]);
        o[2 * i]     = f2us(e * c - od * s);
        o[2 * i + 1] = f2us(od * c + e * s);
    }
    *(u16x8*)dst = o;
}

__launch_bounds__(256)
__global__ void scores_fused(const bf16* __restrict__ xs,
                             const ushort2* __restrict__ csT,
                             bf16* __restrict__ sc) {
    const int h  = blockIdx.z;
    const int s0 = blockIdx.x * 64, t0 = blockIdx.y * 64;
    if (s0 > t0) return;
    __shared__ short As[64][40];
    __shared__ short Bs[64][40];
    const int tid  = threadIdx.x;
    const int srow = tid >> 2, kq = (tid & 3) * 8;
    const int lane = tid & 63, w = tid >> 6, qd = lane >> 4, lc = lane & 15;
    const int tA = t0 + srow, tB = s0 + srow;
    const bf16* gA = xs + (size_t)tA * HN + h * N_DIM + kq;
    const bf16* gB = xs + (size_t)tB * HN + h * N_DIM + kq;
    const ushort2* cA = csT + (size_t)tA * NP2 + (kq >> 1);
    const ushort2* cB = csT + (size_t)tB * NP2 + (kq >> 1);
    f32x4 acc[4] = {{0.f,0.f,0.f,0.f},{0.f,0.f,0.f,0.f},
                    {0.f,0.f,0.f,0.f},{0.f,0.f,0.f,0.f}};
    for (int k0 = 0; k0 < N_DIM; k0 += 32) {
        stage_rope8(&As[srow][kq], gA + k0, cA + (k0 >> 1));
        stage_rope8(&Bs[srow][kq], gB + k0, cB + (k0 >> 1));
        __syncthreads();
        s16x8 a = *(const s16x8*)&As[w * 16 + lc][qd * 8];
        #pragma unroll
        for (int j = 0; j < 4; j++) {
            s16x8 b = *(const s16x8*)&Bs[j * 16 + lc][qd * 8];
            acc[j] = __builtin_amdgcn_mfma_f32_16x16x32_bf16(a, b, acc[j], 0, 0, 0);
        }
        __syncthreads();
    }
    bf16* C = sc + (size_t)h * T_SEQ * T_SEQ;
    const bool diag = (s0 == t0);
    const int tbase = t0 + w * 16 + qd * 4;
    #pragma unroll
    for (int j = 0; j < 4; j++) {
        int s = s0 + j * 16 + lc;
        #pragma unroll
        for (int r = 0; r < 4; r++) {
            int t = tbase + r;
            C[(size_t)t * T_SEQ + s] =
                __float2bfloat16((!diag || s < t) ? acc[j][r] : 0.f);
        }
    }
}

// ---------------------------------------------------------------------------
// dgemm128: 128x128 tile, 4 waves x (64x64), K=192.
// EPI 1: xs = relu(acc); if WQR also qr = rope(relu(acc)) via shfl_xor pair.
// EPI 2: xs *= relu(acc) in place; A advanced to head slab of ykv
//        (n0/N_DIM selects head; each 128-col tile lies within one head).
// ---------------------------------------------------------------------------
template <int EPI, bool WQR>
__launch_bounds__(256)
__global__ void dgemm128(const float* __restrict__ A, const bf16* __restrict__ Bt,
                         bf16* __restrict__ xs, bf16* __restrict__ qr,
                         const ushort2* __restrict__ csT) {
    __shared__ short As[128][40];
    __shared__ short Bs[128][40];

    const int tid = threadIdx.x;
    const int lane = tid & 63, w = tid >> 6, qd = lane >> 4, lc = lane & 15;
    const int wtm = (w >> 1) * 64, wtn = (w & 1) * 64;
    const int n0 = blockIdx.x * 128, m0 = blockIdx.y * 128;
    if constexpr (EPI == 2) A += (size_t)(n0 / N_DIM) * T_SEQ * D_DIM;

    f32x4 acc[4][4] = {};

    for (int k0 = 0; k0 < D_DIM; k0 += 32) {
        #pragma unroll
        for (int c = 0; c < 2; c++) {
            int ch = tid + c * 256;
            int row = ch >> 2, kq = (ch & 3) * 8;
            const float* ga = A + (size_t)(m0 + row) * D_DIM + k0 + kq;
            float4 f0 = *(const float4*)ga;
            float4 f1 = *(const float4*)(ga + 4);
            u16x8 o;
            o[0] = f2us(f0.x); o[1] = f2us(f0.y); o[2] = f2us(f0.z); o[3] = f2us(f0.w);
            o[4] = f2us(f1.x); o[5] = f2us(f1.y); o[6] = f2us(f1.z); o[7] = f2us(f1.w);
            *(u16x8*)&As[row][kq] = o;
            *(u16x8*)&Bs[row][kq] =
                *(const u16x8*)(Bt + (size_t)(n0 + row) * D_DIM + k0 + kq);
        }
        __syncthreads();
        s16x8 a[4], b[4];
        #pragma unroll
        for (int m = 0; m < 4; m++) a[m] = *(const s16x8*)&As[wtm + m * 16 + lc][qd * 8];
        #pragma unroll
        for (int n = 0; n < 4; n++) b[n] = *(const s16x8*)&Bs[wtn + n * 16 + lc][qd * 8];
        #pragma unroll
        for (int m = 0; m < 4; m++)
            #pragma unroll
            for (int n = 0; n < 4; n++)
                acc[m][n] = __builtin_amdgcn_mfma_f32_16x16x32_bf16(a[m], b[n], acc[m][n], 0, 0, 0);
        __syncthreads();
    }

    #pragma unroll
    for (int m = 0; m < 4; m++) {
        #pragma unroll
        for (int r = 0; r < 4; r++) {
            int t = m0 + wtm + m * 16 + qd * 4 + r;
            #pragma unroll
            for (int n = 0; n < 4; n++) {
                int ng = n0 + wtn + n * 16 + lc;
                size_t ci = (size_t)t * HN + ng;
                float v = fmaxf(acc[m][n][r], 0.f);
                if constexpr (EPI == 1) {
                    xs[ci] = __float2bfloat16(v);
                    if constexpr (WQR) {
                        // lanes lc, lc^1 hold (even, odd) of the same rotation pair
                        float pv = __shfl_xor(v, 1, 64);
                        int p = (ng % N_DIM) >> 1;
                        ushort2 cs = csT[(size_t)t * NP2 + p];
                        float c = us2f(cs.x), s = us2f(cs.y);
                        float o = (lc & 1) ? (v * c + pv * s) : (v * c - pv * s);
                        qr[ci] = __float2bfloat16(o);
                    }
                } else {
                    bf16* cp = xs + ci;
                    *cp = __float2bfloat16(b2f(*cp) * v);
                }
            }
        }
    }
}

// ---------------------------------------------------------------------------
// mfma_gemm (64x64): ykv (causal), ymlp split-K slabs, logits. fp32 C store.
// ---------------------------------------------------------------------------
template <typename TA, bool CAUSAL, bool SPLITK>
__launch_bounds__(256)
__global__ void mfma_gemm(const TA* __restrict__ A, const bf16* __restrict__ Bt,
                          float* __restrict__ C,
                          int K, int kSeg, int lda, int ldb, int ldc,
                          long aZ, long bZ, long cZ) {
    __shared__ short As[64][40];
    __shared__ short Bs[64][40];

    const int z = blockIdx.z;
    A += aZ * z;  Bt += bZ * z;  C += cZ * z;

    const int tid = threadIdx.x;
    const int n0 = blockIdx.x * 64, m0 = blockIdx.y * 64;
    const int srow = tid >> 2, sk = (tid & 3) * 8;
    const int lane = tid & 63, w = tid >> 6, qd = lane >> 4, lc = lane & 15;

    int kBeg, kEnd;
    if (SPLITK) { kBeg = z * kSeg; kEnd = kBeg + kSeg; }
    else        { kBeg = 0; kEnd = CAUSAL ? (m0 + 64 < K ? m0 + 64 : K) : K; }

    const TA*   ga = A  + (size_t)(m0 + srow) * lda + sk;
    const bf16* gb = Bt + (size_t)(n0 + srow) * ldb + sk;

    f32x4 acc[4] = {{0.f,0.f,0.f,0.f},{0.f,0.f,0.f,0.f},
                    {0.f,0.f,0.f,0.f},{0.f,0.f,0.f,0.f}};

    for (int k0 = kBeg; k0 < kEnd; k0 += 32) {
        if constexpr (__is_same(TA, float)) {
            float4 f0 = *(const float4*)(ga + k0);
            float4 f1 = *(const float4*)(ga + k0 + 4);
            u16x8 o;
            o[0] = f2us(f0.x); o[1] = f2us(f0.y); o[2] = f2us(f0.z); o[3] = f2us(f0.w);
            o[4] = f2us(f1.x); o[5] = f2us(f1.y); o[6] = f2us(f1.z); o[7] = f2us(f1.w);
            *(u16x8*)&As[srow][sk] = o;
        } else {
            *(u16x8*)&As[srow][sk] = *(const u16x8*)(ga + k0);
        }
        *(u16x8*)&Bs[srow][sk] = *(const u16x8*)(gb + k0);
        __syncthreads();
        s16x8 a = *(const s16x8*)&As[w * 16 + lc][qd * 8];
        #pragma unroll
        for (int j = 0; j < 4; j++) {
            s16x8 b = *(const s16x8*)&Bs[j * 16 + lc][qd * 8];
            acc[j] = __builtin_amdgcn_mfma_f32_16x16x32_bf16(a, b, acc[j], 0, 0, 0);
        }
        __syncthreads();
    }

    #pragma unroll
    for (int j = 0; j < 4; j++) {
        int n = n0 + j * 16 + lc;
        #pragma unroll
        for (int r = 0; r < 4; r++) {
            int m = m0 + w * 16 + qd * 4 + r;
            C[(size_t)m * ldc + n] = acc[j][r];
        }
    }
}

extern "C" void kernel_launch(void* const* d_in, const int* in_sizes, int n_in,
                              void* d_out, int out_size, void* d_ws, size_t ws_size,
                              hipStream_t stream) {
    const int*   idx   = (const int*)  d_in[0];
    const float* dec_x = (const float*)d_in[1];   // (NH, D, N)
    const float* dec_y = (const float*)d_in[2];   // (NH, D, N)
    const float* enc   = (const float*)d_in[3];   // (NH*N, D)
    const float* emb   = (const float*)d_in[4];   // (VOCAB, D)
    const float* pose  = (const float*)d_in[5];   // (BLOCK, D)
    const float* lmh   = (const float*)d_in[6];   // (D, VOCAB)
    float* out = (float*)d_out;                   // (T, VOCAB) fp32

    // workspace layout — identical to passing r8 (ws >= 84,377,600 proven)
    char* wp = (char*)d_ws;
    float*   x    = (float*)wp;              wp += (size_t)T_SEQ * D_DIM * 4;
    bf16*    xs   = (bf16*)wp;               wp += (size_t)T_SEQ * HN * 2;
    ushort2* csT  = (ushort2*)wp;            wp += (size_t)T_SEQ * NP2 * 4;
    bf16*    sc   = (bf16*)wp;               wp += (size_t)NHEAD * T_SEQ * T_SEQ * 2;
    float*   ykv  = (float*)wp;              wp += (size_t)NHEAD * T_SEQ * D_DIM * 4;
    float*   ymlp = (float*)wp;              wp += (size_t)T_SEQ * D_DIM * 4;   // layout keeper
    bf16*    xT   = (bf16*)wp;               wp += (size_t)D_DIM * T_SEQ * 2;
    bf16*    wX   = (bf16*)wp;               wp += (size_t)NHEAD * N_DIM * D_DIM * 2;
    bf16*    wY   = (bf16*)wp;               wp += (size_t)NHEAD * N_DIM * D_DIM * 2;
    bf16*    wE   = (bf16*)wp;               wp += (size_t)D_DIM * HN * 2;
    bf16*    wL   = (bf16*)wp;               wp += (size_t)VOCABSZ * D_DIM * 2;
    const size_t BASE_NEED = (size_t)(wp - (char*)d_ws);
    bf16*    qr   = (bf16*)wp;
    const size_t FULL_NEED = BASE_NEED + (size_t)T_SEQ * HN * 2;
    // ymlp split-K partials overlay sc (dead between ykv-read and next scores-write)
    float* ymlpP = (float*)sc;     // 8 slabs x T*D x 4B = 6,291,456 <= 8,388,608

    if (ws_size < BASE_NEED) {
        fill_out<<<(out_size + 255) / 256, 256, 0, stream>>>(out, (float)ws_size, out_size);
        return;
    }
    const bool USE_QR = (ws_size >= FULL_NEED);

    // weight mirrors (bf16, [n][k])
    t_cvt<<<dim3(48, 3, 4), 256, 0, stream>>>(dec_x, wX, D_DIM, N_DIM,
                                              (long)D_DIM * N_DIM, (long)N_DIM * D_DIM);
    t_cvt<<<dim3(48, 3, 4), 256, 0, stream>>>(dec_y, wY, D_DIM, N_DIM,
                                              (long)D_DIM * N_DIM, (long)N_DIM * D_DIM);
    t_cvt<<<dim3(3, 192, 1), 256, 0, stream>>>(enc, wE, HN, D_DIM, 0L, 0L);
    t_cvt<<<dim3(4, 3, 1), 256, 0, stream>>>(lmh, wL, D_DIM, VOCABSZ, 0L, 0L);

    k_tables<<<(T_SEQ * NP2) / 256, 256, 0, stream>>>(csT);
    k_embed<<<T_SEQ, 64, 0, stream>>>(idx, emb, pose, x);

    for (int l = 0; l < NLAYER; ++l) {
        // xT = x^T (bf16) for ykv's B operand
        t_cvt<<<dim3(3, 16, 1), 256, 0, stream>>>(x, xT, T_SEQ, D_DIM, 0L, 0L);
        // xs = relu(x @ dec_x)  (+ fused qr when available)
        if (USE_QR) {
            dgemm128<1, true><<<dim3(96, 8), 256, 0, stream>>>(x, wX, xs, qr, csT);
            scores128<<<dim3(36, 1, NHEAD), 256, 0, stream>>>(qr, sc);
        } else {
            dgemm128<1, false><<<dim3(96, 8), 256, 0, stream>>>(x, wX, xs, qr, csT);
            scores_fused<<<dim3(16, 16, NHEAD), 256, 0, stream>>>(xs, csT, sc);
        }
        // ykv = sc @ x   (causal)
        mfma_gemm<bf16, true, false><<<dim3(3, 16, NHEAD), 256, 0, stream>>>(
            sc, xT, ykv, T_SEQ, 0, T_SEQ, T_SEQ, D_DIM,
            (long)T_SEQ * T_SEQ, 0L, (long)T_SEQ * D_DIM);
        // ykv = LN(ykv)
        k_ln<<<NHEAD * T_SEQ, 64, 0, stream>>>(ykv);
        // xs *= relu(ykv @ dec_y)   (gate; head slab picked inside kernel)
        dgemm128<2, false><<<dim3(96, 8), 256, 0, stream>>>(
            (const float*)ykv, wY, xs, nullptr, nullptr);
        // ymlp partials = xy @ enc   (split-K=8 -> slabs in sc region)
        mfma_gemm<bf16, false, true><<<dim3(3, 16, 8), 256, 0, stream>>>(
            xs, wE, ymlpP, HN, HN / 8, HN, HN, D_DIM,
            0L, 0L, (long)T_SEQ * D_DIM);
        // x = LN(x + LN(sum partials))
        k_resid8<<<T_SEQ, 64, 0, stream>>>(x, ymlpP);
        (void)ymlp;
    }

    // logits = x @ lm_head
    mfma_gemm<float, false, false><<<dim3(4, 16, 1), 256, 0, stream>>>(
        x, wL, out, D_DIM, 0, D_DIM, D_DIM, VOCABSZ, 0L, 0L, 0L);
}

// Round 12
// 669.483 us; speedup vs baseline: 1.2037x; 1.2037x over previous
//
#include <hip/hip_runtime.h>
#include <hip/hip_bf16.h>

using bf16 = __hip_bfloat16;

#define D_DIM   192
#define N_DIM   3072
#define NHEAD   4
#define T_SEQ   1024
#define HN      12288      // NHEAD * N_DIM
#define NP2     1536       // N_DIM/2
#define VOCABSZ 256
#define NLAYER  4
#define LN_EPS  1e-5f
#define TWO_PI  6.2831853071795864f

typedef __attribute__((ext_vector_type(8))) short          s16x8;
typedef __attribute__((ext_vector_type(8))) unsigned short u16x8;
typedef __attribute__((ext_vector_type(4))) float          f32x4;

__device__ __forceinline__ float b2f(bf16 v) { return __bfloat162float(v); }
__device__ __forceinline__ float us2f(unsigned short u) {
    unsigned int x = ((unsigned int)u) << 16;
    return __builtin_bit_cast(float, x);
}
__device__ __forceinline__ unsigned short f2us(float f) {
    bf16 b = __float2bfloat16(f);
    return __builtin_bit_cast(unsigned short, b);
}

// sentinel: encode ws_size into output (fires only if ws too small)
__global__ void fill_out(float* __restrict__ out, float val, int nelem) {
    int i = blockIdx.x * 256 + threadIdx.x;
    if (i < nelem) out[i] = val;
}

// ---------------------------------------------------------------------------
// Tiled transpose + fp32->bf16: in fp32 [R][C] -> out bf16 [C][R].
// ---------------------------------------------------------------------------
__global__ void t_cvt(const float* __restrict__ in, bf16* __restrict__ out,
                      int R, int C, long inZ, long outZ) {
    __shared__ float tile[64][65];
    in  += inZ  * blockIdx.z;
    out += outZ * blockIdx.z;
    const int tx = threadIdx.x & 63, ty = threadIdx.x >> 6;
    const int r0 = blockIdx.y * 64, c0 = blockIdx.x * 64;
    #pragma unroll
    for (int rr = 0; rr < 16; rr++) {
        int row = ty * 16 + rr;
        tile[row][tx] = in[(size_t)(r0 + row) * C + c0 + tx];
    }
    __syncthreads();
    #pragma unroll
    for (int rr = 0; rr < 16; rr++) {
        int row = ty * 16 + rr;
        out[(size_t)(c0 + row) * R + r0 + tx] = __float2bfloat16(tile[tx][row]);
    }
}

// ---------------------------------------------------------------------------
// Wave-per-row LN family (64 threads/block, 3 elems/lane, butterfly reduce)
// ---------------------------------------------------------------------------
__device__ __forceinline__ void wave_sum2(float& s, float& ss) {
    #pragma unroll
    for (int off = 1; off < 64; off <<= 1) {
        s  += __shfl_xor(s,  off, 64);
        ss += __shfl_xor(ss, off, 64);
    }
}

__global__ void k_embed(const int* __restrict__ idx, const float* __restrict__ emb,
                        const float* __restrict__ pos, float* __restrict__ x) {
    int t = blockIdx.x, l = threadIdx.x;
    int tok = idx[t];
    const float* e = emb + tok * D_DIM;
    const float* p = pos + t * D_DIM;
    float v0 = e[l] + p[l], v1 = e[l + 64] + p[l + 64], v2 = e[l + 128] + p[l + 128];
    float s = v0 + v1 + v2, ss = v0 * v0 + v1 * v1 + v2 * v2;
    wave_sum2(s, ss);
    float m = s / D_DIM, r = rsqrtf(ss / D_DIM - m * m + LN_EPS);
    float* xr = x + t * D_DIM;
    xr[l] = (v0 - m) * r; xr[l + 64] = (v1 - m) * r; xr[l + 128] = (v2 - m) * r;
}

__global__ void k_ln(float* __restrict__ buf) {
    int l = threadIdx.x;
    float* row = buf + (size_t)blockIdx.x * D_DIM;
    float v0 = row[l], v1 = row[l + 64], v2 = row[l + 128];
    float s = v0 + v1 + v2, ss = v0 * v0 + v1 * v1 + v2 * v2;
    wave_sum2(s, ss);
    float m = s / D_DIM, r = rsqrtf(ss / D_DIM - m * m + LN_EPS);
    row[l] = (v0 - m) * r; row[l + 64] = (v1 - m) * r; row[l + 128] = (v2 - m) * r;
}

// x = LN(x + LN(sum of 8 split-K partial slabs))
__global__ void k_resid8(float* __restrict__ x, const float* __restrict__ P) {
    int l = threadIdx.x, t = blockIdx.x;
    float y0 = 0.f, y1 = 0.f, y2 = 0.f;
    #pragma unroll
    for (int p = 0; p < 8; p++) {
        const float* r = P + (size_t)p * T_SEQ * D_DIM + (size_t)t * D_DIM;
        y0 += r[l]; y1 += r[l + 64]; y2 += r[l + 128];
    }
    float* xr = x + (size_t)t * D_DIM;
    float s = y0 + y1 + y2, ss = y0 * y0 + y1 * y1 + y2 * y2;
    wave_sum2(s, ss);
    float m1 = s / D_DIM, r1 = rsqrtf(ss / D_DIM - m1 * m1 + LN_EPS);
    float v0 = xr[l] + (y0 - m1) * r1;
    float v1 = xr[l + 64] + (y1 - m1) * r1;
    float v2 = xr[l + 128] + (y2 - m1) * r1;
    s = v0 + v1 + v2; ss = v0 * v0 + v1 * v1 + v2 * v2;
    wave_sum2(s, ss);
    float m2 = s / D_DIM, r2 = rsqrtf(ss / D_DIM - m2 * m2 + LN_EPS);
    xr[l] = (v0 - m2) * r2; xr[l + 64] = (v1 - m2) * r2; xr[l + 128] = (v2 - m2) * r2;
}

// RoPE cos/sin tables, interleaved bf16 pairs csT[t][p] = (cos, sin)
__global__ void k_tables(ushort2* __restrict__ csT) {
    int gid = blockIdx.x * 256 + threadIdx.x;
    int t = gid / NP2, p = gid % NP2;
    float qf = (float)(2 * p);
    float f = 1.0f / powf(65536.0f, qf / 3072.0f) / (float)TWO_PI;
    float ph = fmodf((float)t * f, 1.0f) * (float)TWO_PI;
    ushort2 cs;
    cs.x = f2us(cosf(ph));
    cs.y = f2us(sinf(ph));
    csT[gid] = cs;
}

// ---------------------------------------------------------------------------
// scores128: sc[h,t,s] = dot(qr[t,h], qr[s,h]) for s<t, else 0.
// 128x128 tile, 4 waves x (64x64), BK=32, triangular grid, DOUBLE-BUFFERED
// LDS pipeline with register prefetch and ONE barrier per K-iter.
// ---------------------------------------------------------------------------
__launch_bounds__(256)
__global__ void scores128(const bf16* __restrict__ qr, bf16* __restrict__ sc) {
    const int h = blockIdx.z;
    int L = blockIdx.x;
    int i = 0;
    while (((i + 1) * (i + 2)) >> 1 <= L) ++i;
    int j = L - ((i * (i + 1)) >> 1);
    const int t0 = i * 128, s0 = j * 128;

    __shared__ short As[2][128][40];
    __shared__ short Bs[2][128][40];

    const int tid = threadIdx.x;
    const int lane = tid & 63, w = tid >> 6, qd = lane >> 4, lc = lane & 15;
    const int wtm = (w >> 1) * 64, wtn = (w & 1) * 64;
    const int r0 = tid >> 2, r1 = r0 + 64;       // staging rows
    const int kq = (tid & 3) * 8;                // staging k-offset

    const bf16* gA = qr + (size_t)t0 * HN + h * N_DIM + kq;
    const bf16* gB = qr + (size_t)s0 * HN + h * N_DIM + kq;

    u16x8 pa0, pa1, pb0, pb1;
    auto prefetch = [&](int k0) {
        pa0 = *(const u16x8*)(gA + (size_t)r0 * HN + k0);
        pa1 = *(const u16x8*)(gA + (size_t)r1 * HN + k0);
        pb0 = *(const u16x8*)(gB + (size_t)r0 * HN + k0);
        pb1 = *(const u16x8*)(gB + (size_t)r1 * HN + k0);
    };
    auto deposit = [&](int buf) {
        *(u16x8*)&As[buf][r0][kq] = pa0;
        *(u16x8*)&As[buf][r1][kq] = pa1;
        *(u16x8*)&Bs[buf][r0][kq] = pb0;
        *(u16x8*)&Bs[buf][r1][kq] = pb1;
    };

    f32x4 acc[4][4] = {};

    prefetch(0);
    deposit(0);
    __syncthreads();

    const int NIT = N_DIM / 32;
    for (int k = 0; k < NIT; k++) {
        const int buf = k & 1;
        const bool more = (k + 1 < NIT);
        if (more) prefetch((k + 1) * 32);
        s16x8 a[4], b[4];
        #pragma unroll
        for (int m = 0; m < 4; m++) a[m] = *(const s16x8*)&As[buf][wtm + m * 16 + lc][qd * 8];
        #pragma unroll
        for (int n = 0; n < 4; n++) b[n] = *(const s16x8*)&Bs[buf][wtn + n * 16 + lc][qd * 8];
        #pragma unroll
        for (int m = 0; m < 4; m++)
            #pragma unroll
            for (int n = 0; n < 4; n++)
                acc[m][n] = __builtin_amdgcn_mfma_f32_16x16x32_bf16(a[m], b[n], acc[m][n], 0, 0, 0);
        if (more) {
            deposit(buf ^ 1);
            __syncthreads();
        }
    }

    bf16* C = sc + (size_t)h * T_SEQ * T_SEQ;
    const bool diag = (i == j);
    #pragma unroll
    for (int m = 0; m < 4; m++) {
        #pragma unroll
        for (int r = 0; r < 4; r++) {
            int t = t0 + wtm + m * 16 + qd * 4 + r;
            #pragma unroll
            for (int n = 0; n < 4; n++) {
                int s = s0 + wtn + n * 16 + lc;
                float v = (diag && s >= t) ? 0.f : acc[m][n][r];
                C[(size_t)t * T_SEQ + s] = __float2bfloat16(v);
            }
        }
    }
}

// ---------------------------------------------------------------------------
// scores fallback (no qr buffer): 64x64, rope fused into staging.
// ---------------------------------------------------------------------------
__device__ __forceinline__ void stage_rope8(short* dst, const bf16* src,
                                            const ushort2* csP) {
    u16x8 v  = *(const u16x8*)src;
    u16x8 cs = *(const u16x8*)csP;
    u16x8 o;
    #pragma unroll
    for (int i = 0; i < 4; i++) {
        float e  = us2f(v[2 * i]), od = us2f(v[2 * i + 1]);
        float c  = us2f(cs[2 * i]), s = us2f(cs[2 * i + 1]);
        o[2 * i]     = f2us(e * c - od * s);
        o[2 * i + 1] = f2us(od * c + e * s);
    }
    *(u16x8*)dst = o;
}

__launch_bounds__(256)
__global__ void scores_fused(const bf16* __restrict__ xs,
                             const ushort2* __restrict__ csT,
                             bf16* __restrict__ sc) {
    const int h  = blockIdx.z;
    const int s0 = blockIdx.x * 64, t0 = blockIdx.y * 64;
    if (s0 > t0) return;
    __shared__ short As[64][40];
    __shared__ short Bs[64][40];
    const int tid  = threadIdx.x;
    const int srow = tid >> 2, kq = (tid & 3) * 8;
    const int lane = tid & 63, w = tid >> 6, qd = lane >> 4, lc = lane & 15;
    const int tA = t0 + srow, tB = s0 + srow;
    const bf16* gA = xs + (size_t)tA * HN + h * N_DIM + kq;
    const bf16* gB = xs + (size_t)tB * HN + h * N_DIM + kq;
    const ushort2* cA = csT + (size_t)tA * NP2 + (kq >> 1);
    const ushort2* cB = csT + (size_t)tB * NP2 + (kq >> 1);
    f32x4 acc[4] = {{0.f,0.f,0.f,0.f},{0.f,0.f,0.f,0.f},
                    {0.f,0.f,0.f,0.f},{0.f,0.f,0.f,0.f}};
    for (int k0 = 0; k0 < N_DIM; k0 += 32) {
        stage_rope8(&As[srow][kq], gA + k0, cA + (k0 >> 1));
        stage_rope8(&Bs[srow][kq], gB + k0, cB + (k0 >> 1));
        __syncthreads();
        s16x8 a = *(const s16x8*)&As[w * 16 + lc][qd * 8];
        #pragma unroll
        for (int j = 0; j < 4; j++) {
            s16x8 b = *(const s16x8*)&Bs[j * 16 + lc][qd * 8];
            acc[j] = __builtin_amdgcn_mfma_f32_16x16x32_bf16(a, b, acc[j], 0, 0, 0);
        }
        __syncthreads();
    }
    bf16* C = sc + (size_t)h * T_SEQ * T_SEQ;
    const bool diag = (s0 == t0);
    const int tbase = t0 + w * 16 + qd * 4;
    #pragma unroll
    for (int j = 0; j < 4; j++) {
        int s = s0 + j * 16 + lc;
        #pragma unroll
        for (int r = 0; r < 4; r++) {
            int t = tbase + r;
            C[(size_t)t * T_SEQ + s] =
                __float2bfloat16((!diag || s < t) ? acc[j][r] : 0.f);
        }
    }
}

// ---------------------------------------------------------------------------
// dgemm128: 128x128 tile, 4 waves x (64x64), K=192, double-buffered pipeline.
// EPI 1: xs = relu(acc); if WQR also qr = rope(relu(acc)) via shfl_xor pair.
// EPI 2: xs *= relu(acc) in place; A advanced to head slab of ykv.
// ---------------------------------------------------------------------------
template <int EPI, bool WQR>
__launch_bounds__(256)
__global__ void dgemm128(const float* __restrict__ A, const bf16* __restrict__ Bt,
                         bf16* __restrict__ xs, bf16* __restrict__ qr,
                         const ushort2* __restrict__ csT) {
    __shared__ short As[2][128][40];
    __shared__ short Bs[2][128][40];

    const int tid = threadIdx.x;
    const int lane = tid & 63, w = tid >> 6, qd = lane >> 4, lc = lane & 15;
    const int wtm = (w >> 1) * 64, wtn = (w & 1) * 64;
    const int n0 = blockIdx.x * 128, m0 = blockIdx.y * 128;
    if constexpr (EPI == 2) A += (size_t)(n0 / N_DIM) * T_SEQ * D_DIM;

    const int r0 = tid >> 2, r1 = r0 + 64;
    const int kq = (tid & 3) * 8;

    const float* gA = A  + kq;
    const bf16*  gB = Bt + kq;

    float4 fa0, fa1, fa2, fa3;
    u16x8 pb0, pb1;
    auto prefetch = [&](int k0) {
        const float* a0 = gA + (size_t)(m0 + r0) * D_DIM + k0;
        const float* a1 = gA + (size_t)(m0 + r1) * D_DIM + k0;
        fa0 = *(const float4*)a0; fa1 = *(const float4*)(a0 + 4);
        fa2 = *(const float4*)a1; fa3 = *(const float4*)(a1 + 4);
        pb0 = *(const u16x8*)(gB + (size_t)(n0 + r0) * D_DIM + k0);
        pb1 = *(const u16x8*)(gB + (size_t)(n0 + r1) * D_DIM + k0);
    };
    auto deposit = [&](int buf) {
        u16x8 o0, o1;
        o0[0] = f2us(fa0.x); o0[1] = f2us(fa0.y); o0[2] = f2us(fa0.z); o0[3] = f2us(fa0.w);
        o0[4] = f2us(fa1.x); o0[5] = f2us(fa1.y); o0[6] = f2us(fa1.z); o0[7] = f2us(fa1.w);
        o1[0] = f2us(fa2.x); o1[1] = f2us(fa2.y); o1[2] = f2us(fa2.z); o1[3] = f2us(fa2.w);
        o1[4] = f2us(fa3.x); o1[5] = f2us(fa3.y); o1[6] = f2us(fa3.z); o1[7] = f2us(fa3.w);
        *(u16x8*)&As[buf][r0][kq] = o0;
        *(u16x8*)&As[buf][r1][kq] = o1;
        *(u16x8*)&Bs[buf][r0][kq] = pb0;
        *(u16x8*)&Bs[buf][r1][kq] = pb1;
    };

    f32x4 acc[4][4] = {};

    prefetch(0);
    deposit(0);
    __syncthreads();

    const int NIT = D_DIM / 32;
    for (int k = 0; k < NIT; k++) {
        const int buf = k & 1;
        const bool more = (k + 1 < NIT);
        if (more) prefetch((k + 1) * 32);
        s16x8 a[4], b[4];
        #pragma unroll
        for (int m = 0; m < 4; m++) a[m] = *(const s16x8*)&As[buf][wtm + m * 16 + lc][qd * 8];
        #pragma unroll
        for (int n = 0; n < 4; n++) b[n] = *(const s16x8*)&Bs[buf][wtn + n * 16 + lc][qd * 8];
        #pragma unroll
        for (int m = 0; m < 4; m++)
            #pragma unroll
            for (int n = 0; n < 4; n++)
                acc[m][n] = __builtin_amdgcn_mfma_f32_16x16x32_bf16(a[m], b[n], acc[m][n], 0, 0, 0);
        if (more) {
            deposit(buf ^ 1);
            __syncthreads();
        }
    }

    #pragma unroll
    for (int m = 0; m < 4; m++) {
        #pragma unroll
        for (int r = 0; r < 4; r++) {
            int t = m0 + wtm + m * 16 + qd * 4 + r;
            #pragma unroll
            for (int n = 0; n < 4; n++) {
                int ng = n0 + wtn + n * 16 + lc;
                size_t ci = (size_t)t * HN + ng;
                float v = fmaxf(acc[m][n][r], 0.f);
                if constexpr (EPI == 1) {
                    xs[ci] = __float2bfloat16(v);
                    if constexpr (WQR) {
                        float pv = __shfl_xor(v, 1, 64);
                        int p = (ng % N_DIM) >> 1;
                        ushort2 cs = csT[(size_t)t * NP2 + p];
                        float c = us2f(cs.x), s = us2f(cs.y);
                        float o = (lc & 1) ? (v * c + pv * s) : (v * c - pv * s);
                        qr[ci] = __float2bfloat16(o);
                    }
                } else {
                    bf16* cp = xs + ci;
                    *cp = __float2bfloat16(b2f(*cp) * v);
                }
            }
        }
    }
}

// ---------------------------------------------------------------------------
// mfma_gemm (64x64, double-buffered): ykv (causal), ymlp slabs, logits.
// ---------------------------------------------------------------------------
template <typename TA, bool CAUSAL, bool SPLITK>
__launch_bounds__(256)
__global__ void mfma_gemm(const TA* __restrict__ A, const bf16* __restrict__ Bt,
                          float* __restrict__ C,
                          int K, int kSeg, int lda, int ldb, int ldc,
                          long aZ, long bZ, long cZ) {
    __shared__ short As[2][64][40];
    __shared__ short Bs[2][64][40];

    const int z = blockIdx.z;
    A += aZ * z;  Bt += bZ * z;  C += cZ * z;

    const int tid = threadIdx.x;
    const int n0 = blockIdx.x * 64, m0 = blockIdx.y * 64;
    const int srow = tid >> 2, sk = (tid & 3) * 8;
    const int lane = tid & 63, w = tid >> 6, qd = lane >> 4, lc = lane & 15;

    int kBeg, kEnd;
    if (SPLITK) { kBeg = z * kSeg; kEnd = kBeg + kSeg; }
    else        { kBeg = 0; kEnd = CAUSAL ? (m0 + 64 < K ? m0 + 64 : K) : K; }

    const TA*   ga = A  + (size_t)(m0 + srow) * lda + sk;
    const bf16* gb = Bt + (size_t)(n0 + srow) * ldb + sk;

    float4 f0, f1;
    u16x8 paw, pbw;
    auto prefetch = [&](int k0) {
        if constexpr (__is_same(TA, float)) {
            f0 = *(const float4*)(ga + k0);
            f1 = *(const float4*)(ga + k0 + 4);
        } else {
            paw = *(const u16x8*)(ga + k0);
        }
        pbw = *(const u16x8*)(gb + k0);
    };
    auto deposit = [&](int buf) {
        if constexpr (__is_same(TA, float)) {
            u16x8 o;
            o[0] = f2us(f0.x); o[1] = f2us(f0.y); o[2] = f2us(f0.z); o[3] = f2us(f0.w);
            o[4] = f2us(f1.x); o[5] = f2us(f1.y); o[6] = f2us(f1.z); o[7] = f2us(f1.w);
            *(u16x8*)&As[buf][srow][sk] = o;
        } else {
            *(u16x8*)&As[buf][srow][sk] = paw;
        }
        *(u16x8*)&Bs[buf][srow][sk] = pbw;
    };

    f32x4 acc[4] = {{0.f,0.f,0.f,0.f},{0.f,0.f,0.f,0.f},
                    {0.f,0.f,0.f,0.f},{0.f,0.f,0.f,0.f}};

    const int NIT = (kEnd - kBeg) / 32;
    prefetch(kBeg);
    deposit(0);
    __syncthreads();

    for (int k = 0; k < NIT; k++) {
        const int buf = k & 1;
        const bool more = (k + 1 < NIT);
        if (more) prefetch(kBeg + (k + 1) * 32);
        s16x8 a = *(const s16x8*)&As[buf][w * 16 + lc][qd * 8];
        s16x8 b[4];
        #pragma unroll
        for (int j = 0; j < 4; j++) b[j] = *(const s16x8*)&Bs[buf][j * 16 + lc][qd * 8];
        #pragma unroll
        for (int j = 0; j < 4; j++)
            acc[j] = __builtin_amdgcn_mfma_f32_16x16x32_bf16(a, b[j], acc[j], 0, 0, 0);
        if (more) {
            deposit(buf ^ 1);
            __syncthreads();
        }
    }

    #pragma unroll
    for (int j = 0; j < 4; j++) {
        int n = n0 + j * 16 + lc;
        #pragma unroll
        for (int r = 0; r < 4; r++) {
            int m = m0 + w * 16 + qd * 4 + r;
            C[(size_t)m * ldc + n] = acc[j][r];
        }
    }
}

extern "C" void kernel_launch(void* const* d_in, const int* in_sizes, int n_in,
                              void* d_out, int out_size, void* d_ws, size_t ws_size,
                              hipStream_t stream) {
    const int*   idx   = (const int*)  d_in[0];
    const float* dec_x = (const float*)d_in[1];   // (NH, D, N)
    const float* dec_y = (const float*)d_in[2];   // (NH, D, N)
    const float* enc   = (const float*)d_in[3];   // (NH*N, D)
    const float* emb   = (const float*)d_in[4];   // (VOCAB, D)
    const float* pose  = (const float*)d_in[5];   // (BLOCK, D)
    const float* lmh   = (const float*)d_in[6];   // (D, VOCAB)
    float* out = (float*)d_out;                   // (T, VOCAB) fp32

    // workspace layout — identical to passing r11 (ws >= 84,377,600 proven)
    char* wp = (char*)d_ws;
    float*   x    = (float*)wp;              wp += (size_t)T_SEQ * D_DIM * 4;
    bf16*    xs   = (bf16*)wp;               wp += (size_t)T_SEQ * HN * 2;
    ushort2* csT  = (ushort2*)wp;            wp += (size_t)T_SEQ * NP2 * 4;
    bf16*    sc   = (bf16*)wp;               wp += (size_t)NHEAD * T_SEQ * T_SEQ * 2;
    float*   ykv  = (float*)wp;              wp += (size_t)NHEAD * T_SEQ * D_DIM * 4;
    float*   ymlp = (float*)wp;              wp += (size_t)T_SEQ * D_DIM * 4;   // layout keeper
    bf16*    xT   = (bf16*)wp;               wp += (size_t)D_DIM * T_SEQ * 2;
    bf16*    wX   = (bf16*)wp;               wp += (size_t)NHEAD * N_DIM * D_DIM * 2;
    bf16*    wY   = (bf16*)wp;               wp += (size_t)NHEAD * N_DIM * D_DIM * 2;
    bf16*    wE   = (bf16*)wp;               wp += (size_t)D_DIM * HN * 2;
    bf16*    wL   = (bf16*)wp;               wp += (size_t)VOCABSZ * D_DIM * 2;
    const size_t BASE_NEED = (size_t)(wp - (char*)d_ws);
    bf16*    qr   = (bf16*)wp;
    const size_t FULL_NEED = BASE_NEED + (size_t)T_SEQ * HN * 2;
    float* ymlpP = (float*)sc;     // 8 slabs x T*D x 4B overlay on dead sc region

    if (ws_size < BASE_NEED) {
        fill_out<<<(out_size + 255) / 256, 256, 0, stream>>>(out, (float)ws_size, out_size);
        return;
    }
    const bool USE_QR = (ws_size >= FULL_NEED);

    // weight mirrors (bf16, [n][k])
    t_cvt<<<dim3(48, 3, 4), 256, 0, stream>>>(dec_x, wX, D_DIM, N_DIM,
                                              (long)D_DIM * N_DIM, (long)N_DIM * D_DIM);
    t_cvt<<<dim3(48, 3, 4), 256, 0, stream>>>(dec_y, wY, D_DIM, N_DIM,
                                              (long)D_DIM * N_DIM, (long)N_DIM * D_DIM);
    t_cvt<<<dim3(3, 192, 1), 256, 0, stream>>>(enc, wE, HN, D_DIM, 0L, 0L);
    t_cvt<<<dim3(4, 3, 1), 256, 0, stream>>>(lmh, wL, D_DIM, VOCABSZ, 0L, 0L);

    k_tables<<<(T_SEQ * NP2) / 256, 256, 0, stream>>>(csT);
    k_embed<<<T_SEQ, 64, 0, stream>>>(idx, emb, pose, x);

    for (int l = 0; l < NLAYER; ++l) {
        // xT = x^T (bf16) for ykv's B operand
        t_cvt<<<dim3(3, 16, 1), 256, 0, stream>>>(x, xT, T_SEQ, D_DIM, 0L, 0L);
        // xs = relu(x @ dec_x)  (+ fused qr when available)
        if (USE_QR) {
            dgemm128<1, true><<<dim3(96, 8), 256, 0, stream>>>(x, wX, xs, qr, csT);
            scores128<<<dim3(36, 1, NHEAD), 256, 0, stream>>>(qr, sc);
        } else {
            dgemm128<1, false><<<dim3(96, 8), 256, 0, stream>>>(x, wX, xs, qr, csT);
            scores_fused<<<dim3(16, 16, NHEAD), 256, 0, stream>>>(xs, csT, sc);
        }
        // ykv = sc @ x   (causal)
        mfma_gemm<bf16, true, false><<<dim3(3, 16, NHEAD), 256, 0, stream>>>(
            sc, xT, ykv, T_SEQ, 0, T_SEQ, T_SEQ, D_DIM,
            (long)T_SEQ * T_SEQ, 0L, (long)T_SEQ * D_DIM);
        // ykv = LN(ykv)
        k_ln<<<NHEAD * T_SEQ, 64, 0, stream>>>(ykv);
        // xs *= relu(ykv @ dec_y)   (gate; head slab picked inside kernel)
        dgemm128<2, false><<<dim3(96, 8), 256, 0, stream>>>(
            (const float*)ykv, wY, xs, nullptr, nullptr);
        // ymlp partials = xy @ enc   (split-K=8 -> slabs in sc region)
        mfma_gemm<bf16, false, true><<<dim3(3, 16, 8), 256, 0, stream>>>(
            xs, wE, ymlpP, HN, HN / 8, HN, HN, D_DIM,
            0L, 0L, (long)T_SEQ * D_DIM);
        // x = LN(x + LN(sum partials))
        k_resid8<<<T_SEQ, 64, 0, stream>>>(x, ymlpP);
        (void)ymlp;
    }

    // logits = x @ lm_head
    mfma_gemm<float, false, false><<<dim3(4, 16, 1), 256, 0, stream>>>(
        x, wL, out, D_DIM, 0, D_DIM, D_DIM, VOCABSZ, 0L, 0L, 0L);
}